// Round 3
// baseline (492.637 us; speedup 1.0000x reference)
//
#include <hip/hip_runtime.h>
#include <math.h>

// Problem constants (from reference)
#define BB 4
#define SS 8192
#define DD 2048
#define RKHS 1024
#define EMBD 128
#define NE 64
#define NTOK (BB * SS)          // 32768

typedef __attribute__((ext_vector_type(8))) _Float16 half8;
typedef __attribute__((ext_vector_type(2))) _Float16 half2v;
typedef __attribute__((ext_vector_type(4))) float f32x4;

// Workspace layout (max concurrent 768KB+256B):
//   remb  fp32[1024][64]        @ 0        live K1->K2
//   Cpack half2(hi,lo)[2048][64]@ 256K     live K2->K3 (scaled 2^12)
//   Bsw   uint4[32768]          @ 0        live K3->K4 (overwrites remb)
//   c0    fp32[64]              @ 768K     live K2->K4
#define REMB_OFF  0
#define CPACK_OFF (256 * 1024)
#define BSW_OFF   0
#define C0_OFF    (768 * 1024)

// ---------------------------------------------------------------------------
// K1: remb[r][e] = sum_d embeddings[e][d]*W_exp[r][d] + b_exp[r]  (fp64 acc)
// grid 256 x 256: block covers 4 r's x 64 e's. float4 loads (emb L1-resident,
// W_exp row wave-uniform broadcast).
// ---------------------------------------------------------------------------
__global__ __launch_bounds__(256) void k_emb(
    const float* __restrict__ emb, const float* __restrict__ W_exp,
    const float* __restrict__ b_exp, float* __restrict__ remb) {
  int u = threadIdx.x;
  int e = u & 63;
  int r = blockIdx.x * 4 + (u >> 6);
  const float* er = emb + (size_t)e * EMBD;
  const float* wr = W_exp + (size_t)r * EMBD;
  double a = (double)b_exp[r];
#pragma unroll 8
  for (int d4 = 0; d4 < EMBD / 4; ++d4) {
    float4 ev = *(const float4*)(er + d4 * 4);
    float4 wv = *(const float4*)(wr + d4 * 4);
    a += (double)ev.x * (double)wv.x;
    a += (double)ev.y * (double)wv.y;
    a += (double)ev.z * (double)wv.z;
    a += (double)ev.w * (double)wv.w;
  }
  remb[(size_t)r * NE + e] = (float)a;
}

// ---------------------------------------------------------------------------
// K2: C[d][e] = sum_r W_hid[r][d]*remb[r][e]  (fp64 acc), stored as fp16
// (hi,lo) of C*4096.  Blocks 0..127: tile of 16 d x 64 e, r staged in LDS
// chunks of 64 (W_hid read coalesced along d -> read exactly once).
// Thread: dl = u&15, eg = u>>4, 4 e's each (fp64 acc[4]).
// Block 128: c0[e] = sum_r b_hid[r]*remb[r][e] (4-way r split + LDS reduce).
// ---------------------------------------------------------------------------
__global__ __launch_bounds__(256) void k_proj(
    const float* __restrict__ W_hid, const float* __restrict__ b_hid,
    const float* __restrict__ remb, half2v* __restrict__ Cpack,
    float* __restrict__ c0) {
  int u = threadIdx.x;
  if (blockIdx.x == 128) {
    __shared__ double red[4][64];
    int e = u & 63, rq = u >> 6;
    double acc = 0.0;
#pragma unroll 8
    for (int i = 0; i < 256; ++i) {
      int r = rq * 256 + i;
      acc += (double)b_hid[r] * (double)remb[(size_t)r * NE + e];
    }
    red[rq][e] = acc;
    __syncthreads();
    if (u < 64) c0[u] = (float)(red[0][u] + red[1][u] + red[2][u] + red[3][u]);
    return;
  }

  __shared__ float Wl[64][16];   // 4 KB
  __shared__ float Rl[64][64];   // 16 KB
  const int dl = u & 15;
  const int eg = u >> 4;         // 0..15
  const int d0 = blockIdx.x * 16;
  double acc[4] = {0.0, 0.0, 0.0, 0.0};

  for (int r0 = 0; r0 < RKHS; r0 += 64) {
    __syncthreads();
    // stage W tile: 64 r x 16 d (rows coalesced)
#pragma unroll
    for (int i = 0; i < 4; ++i) {
      int qq = i * 256 + u;
      Wl[qq >> 4][qq & 15] = W_hid[(size_t)(r0 + (qq >> 4)) * DD + d0 + (qq & 15)];
    }
    // stage remb tile: 64 r x 64 e (rows coalesced)
#pragma unroll
    for (int i = 0; i < 16; ++i) {
      int qq = i * 256 + u;
      Rl[qq >> 6][qq & 63] = remb[(size_t)(r0 + (qq >> 6)) * NE + (qq & 63)];
    }
    __syncthreads();
#pragma unroll 8
    for (int rr = 0; rr < 64; ++rr) {
      double wv = (double)Wl[rr][dl];
#pragma unroll
      for (int j = 0; j < 4; ++j)
        acc[j] += wv * (double)Rl[rr][eg * 4 + j];
    }
  }
#pragma unroll
  for (int j = 0; j < 4; ++j) {
    float c = (float)(acc[j] * 4096.0);  // 2^12: keeps lo out of fp16 subnormals
    _Float16 hi = (_Float16)c;
    _Float16 lo = (_Float16)(c - (float)hi);
    half2v p; p.x = hi; p.y = lo;
    Cpack[(size_t)(d0 + dl) * NE + eg * 4 + j] = p;
  }
}

// ---------------------------------------------------------------------------
// K3: pre-swizzle Cpack into MFMA B-fragment order.
// Fragment for (kk, group g, half h): lane l holds 8 fp16 =
//   C16[k = kk*32 + (l>>4)*8 + j][n = g*16 + (l&15)], j=0..7, packed 16B.
// Bsw uint4 index = ((kk*4+g)*2+h)*64 + l  == flat thread id.
// ---------------------------------------------------------------------------
__global__ __launch_bounds__(256) void k_swz(
    const half2v* __restrict__ Cpack, uint4* __restrict__ Bsw) {
  int flat = blockIdx.x * 256 + threadIdx.x;   // 0..32767
  int lane = flat & 63;
  int h = (flat >> 6) & 1;
  int g = (flat >> 7) & 3;
  int kk = flat >> 9;
  int n = g * 16 + (lane & 15);
  int kb = kk * 32 + ((lane >> 4) & 3) * 8;
  half8 v;
#pragma unroll
  for (int j = 0; j < 8; ++j) {
    half2v p = Cpack[(size_t)(kb + j) * NE + n];
    v[j] = h ? p.y : p.x;
  }
  Bsw[flat] = __builtin_bit_cast(uint4, v);
}

// ---------------------------------------------------------------------------
// K4: main router. 2048 blocks x 128 threads (2 waves; wave w owns K-half w).
// Software-pipelined, barrier-free K loop (32 kk-steps of K=32):
//   - B fragments double-buffered (prefetch kk+1 before consuming kk)
//   - A stream prefetch depth 2 (prefetch kk+2)
//   issue order per iter: B(kk+1), A(kk+2), consume(kk) -> the vmcnt wait
//   for B(kk) leaves the newer A loads in flight (HBM latency hidden).
// 3-pass fp16-split MFMA (hh, hl, lh) into fp32 acc; epilogue combines the
// two K-halves in LDS, lanes 0..15 do top-2 + softmax.
// ---------------------------------------------------------------------------
#define PF 2

__global__ __launch_bounds__(128, 3) void kernel_router(
    const float* __restrict__ in, const uint4* __restrict__ Bsw,
    const float* __restrict__ c0, float* __restrict__ out) {
  __shared__ float Lg[2][16][65];
  const int tid = threadIdx.x;
  const int l = tid & 63;
  const int w = tid >> 6;                     // K-half
  const size_t tok0 = (size_t)blockIdx.x * 16;
  const int q = (l >> 4) & 3;                 // quad
  const int col = l & 15;
  const float* arow = in + (tok0 + col) * DD + (size_t)w * (DD / 2) + q * 8;
  const uint4* bbase = Bsw + (size_t)w * 32 * 512 + l;

  f32x4 acc0 = {0.f, 0.f, 0.f, 0.f};
  f32x4 acc1 = {0.f, 0.f, 0.f, 0.f};
  f32x4 acc2 = {0.f, 0.f, 0.f, 0.f};
  f32x4 acc3 = {0.f, 0.f, 0.f, 0.f};

  float4 a0b[PF], a1b[PF];
  uint4 bh[2][4], bl[2][4];

  // prologue: A(0..PF-1), B(0)
#pragma unroll
  for (int i = 0; i < PF; ++i) {
    a0b[i] = *(const float4*)(arow + i * 32);
    a1b[i] = *(const float4*)(arow + i * 32 + 4);
  }
  {
    const uint4* bq = bbase;
    bh[0][0] = bq[0];   bl[0][0] = bq[64];
    bh[0][1] = bq[128]; bl[0][1] = bq[192];
    bh[0][2] = bq[256]; bl[0][2] = bq[320];
    bh[0][3] = bq[384]; bl[0][3] = bq[448];
  }

#pragma unroll 2
  for (int kk = 0; kk < 32; ++kk) {
    const int cur = kk & 1;
    // prefetch B(kk+1) into the other buffer (clamped: last iter re-reads 31)
    {
      const int nb = (kk + 1 < 32) ? (kk + 1) : 31;
      const uint4* bq = bbase + (size_t)nb * 512;
      bh[cur ^ 1][0] = bq[0];   bl[cur ^ 1][0] = bq[64];
      bh[cur ^ 1][1] = bq[128]; bl[cur ^ 1][1] = bq[192];
      bh[cur ^ 1][2] = bq[256]; bl[cur ^ 1][2] = bq[320];
      bh[cur ^ 1][3] = bq[384]; bl[cur ^ 1][3] = bq[448];
    }
    // consume A(kk), refill slot with A(kk+PF) (clamped)
    const float4 ca0 = a0b[cur];
    const float4 ca1 = a1b[cur];
    {
      const int na = (kk + PF < 32) ? (kk + PF) : 31;
      a0b[cur] = *(const float4*)(arow + na * 32);
      a1b[cur] = *(const float4*)(arow + na * 32 + 4);
    }

    const float av[8] = {ca0.x, ca0.y, ca0.z, ca0.w, ca1.x, ca1.y, ca1.z, ca1.w};
    half8 ah, al;
#pragma unroll
    for (int j = 0; j < 8; ++j) {
      _Float16 hi = (_Float16)av[j];
      ah[j] = hi;
      al[j] = (_Float16)(av[j] - (float)hi);
    }
    const half8 bh0 = __builtin_bit_cast(half8, bh[cur][0]), bl0 = __builtin_bit_cast(half8, bl[cur][0]);
    const half8 bh1 = __builtin_bit_cast(half8, bh[cur][1]), bl1 = __builtin_bit_cast(half8, bl[cur][1]);
    const half8 bh2 = __builtin_bit_cast(half8, bh[cur][2]), bl2 = __builtin_bit_cast(half8, bl[cur][2]);
    const half8 bh3 = __builtin_bit_cast(half8, bh[cur][3]), bl3 = __builtin_bit_cast(half8, bl[cur][3]);

    acc0 = __builtin_amdgcn_mfma_f32_16x16x32_f16(ah, bh0, acc0, 0, 0, 0);
    acc1 = __builtin_amdgcn_mfma_f32_16x16x32_f16(ah, bh1, acc1, 0, 0, 0);
    acc2 = __builtin_amdgcn_mfma_f32_16x16x32_f16(ah, bh2, acc2, 0, 0, 0);
    acc3 = __builtin_amdgcn_mfma_f32_16x16x32_f16(ah, bh3, acc3, 0, 0, 0);
    acc0 = __builtin_amdgcn_mfma_f32_16x16x32_f16(al, bh0, acc0, 0, 0, 0);
    acc1 = __builtin_amdgcn_mfma_f32_16x16x32_f16(al, bh1, acc1, 0, 0, 0);
    acc2 = __builtin_amdgcn_mfma_f32_16x16x32_f16(al, bh2, acc2, 0, 0, 0);
    acc3 = __builtin_amdgcn_mfma_f32_16x16x32_f16(al, bh3, acc3, 0, 0, 0);
    acc0 = __builtin_amdgcn_mfma_f32_16x16x32_f16(ah, bl0, acc0, 0, 0, 0);
    acc1 = __builtin_amdgcn_mfma_f32_16x16x32_f16(ah, bl1, acc1, 0, 0, 0);
    acc2 = __builtin_amdgcn_mfma_f32_16x16x32_f16(ah, bl2, acc2, 0, 0, 0);
    acc3 = __builtin_amdgcn_mfma_f32_16x16x32_f16(ah, bl3, acc3, 0, 0, 0);
  }

  // epilogue: descale; wave 0 adds bias. C/D layout: col=lane&15, row=q*4+r.
  {
    const float inv = 1.0f / 4096.0f;
    const float base0 = w ? 0.f : c0[col];
    const float base1 = w ? 0.f : c0[16 + col];
    const float base2 = w ? 0.f : c0[32 + col];
    const float base3 = w ? 0.f : c0[48 + col];
#pragma unroll
    for (int r = 0; r < 4; ++r) {
      Lg[w][q * 4 + r][col]      = acc0[r] * inv + base0;
      Lg[w][q * 4 + r][16 + col] = acc1[r] * inv + base1;
      Lg[w][q * 4 + r][32 + col] = acc2[r] * inv + base2;
      Lg[w][q * 4 + r][48 + col] = acc3[r] * inv + base3;
    }
  }
  __syncthreads();

  if (tid < 16) {
    float m1 = Lg[0][tid][0] + Lg[1][tid][0];
    int i1 = 0;
#pragma unroll 8
    for (int e = 1; e < NE; ++e) {
      float v = Lg[0][tid][e] + Lg[1][tid][e];
      if (v > m1) { m1 = v; i1 = e; }
    }
    int i2 = (i1 == 0) ? 1 : 0;
    float m2 = Lg[0][tid][i2] + Lg[1][tid][i2];
#pragma unroll 8
    for (int e = 0; e < NE; ++e) {
      if (e == i1) continue;
      float v = Lg[0][tid][e] + Lg[1][tid][e];
      if (v > m2) { m2 = v; i2 = e; }
    }
    double ex = exp((double)m2 - (double)m1);
    double denom = 1.0 + ex;
    float rw1 = (float)(1.0 / denom);
    float rw2 = (float)(ex / denom);

    const size_t tg = tok0 + tid;
    *(float2*)(out + tg * 2) = make_float2((float)i1, (float)i2);
    *(float2*)(out + (size_t)NTOK * 2 + tg * 2) = make_float2(rw1, rw2);
  }
  // aux loss analytically constant: (K/E * 1/2) * E^2 = 64.0
  if (blockIdx.x == 0 && tid == 0) out[(size_t)NTOK * 4] = 64.0f;
}

// ---------------------------------------------------------------------------
extern "C" void kernel_launch(void* const* d_in, const int* in_sizes, int n_in,
                              void* d_out, int out_size, void* d_ws,
                              size_t ws_size, hipStream_t stream) {
  const float* input = (const float*)d_in[0];   // [4,8192,2048]
  const float* W_hid = (const float*)d_in[1];   // [1024,2048]
  const float* b_hid = (const float*)d_in[2];   // [1024]
  const float* W_exp = (const float*)d_in[3];   // [1024,128]
  const float* b_exp = (const float*)d_in[4];   // [1024]
  const float* emb = (const float*)d_in[5];     // [64,128]
  float* out = (float*)d_out;

  float* remb = (float*)((char*)d_ws + REMB_OFF);
  half2v* Cpack = (half2v*)((char*)d_ws + CPACK_OFF);
  uint4* Bsw = (uint4*)((char*)d_ws + BSW_OFF);
  float* c0 = (float*)((char*)d_ws + C0_OFF);

  k_emb<<<RKHS / 4, 256, 0, stream>>>(emb, W_exp, b_exp, remb);
  k_proj<<<129, 256, 0, stream>>>(W_hid, b_hid, remb, Cpack, c0);
  k_swz<<<128, 256, 0, stream>>>(Cpack, Bsw);
  kernel_router<<<NTOK / 16, 128, 0, stream>>>(input, Bsw, c0, out);
}

// Round 4
// 466.272 us; speedup vs baseline: 1.0565x; 1.0565x over previous
//
#include <hip/hip_runtime.h>
#include <math.h>

// Problem constants (from reference)
#define BB 4
#define SS 8192
#define DD 2048
#define RKHS 1024
#define EMBD 128
#define NE 64
#define NTOK (BB * SS)          // 32768

typedef __attribute__((ext_vector_type(8))) _Float16 half8;
typedef __attribute__((ext_vector_type(2))) _Float16 half2v;
typedef __attribute__((ext_vector_type(4))) float f32x4;

// Workspace layout (max concurrent 768KB+256B):
//   remb  fp32[1024][64]        @ 0        live K1->K2
//   Cpack half2(hi,lo)[2048][64]@ 256K     live K2->K3 (scaled 2^12)
//   Bsw   uint4[32768]          @ 0        live K3->K4 (overwrites remb)
//   c0    fp32[64]              @ 768K     live K2->K4
#define REMB_OFF  0
#define CPACK_OFF (256 * 1024)
#define BSW_OFF   0
#define C0_OFF    (768 * 1024)

// ---------------------------------------------------------------------------
// K1: remb[r][e] = sum_d embeddings[e][d]*W_exp[r][d] + b_exp[r]  (fp64 acc)
// ---------------------------------------------------------------------------
__global__ __launch_bounds__(256) void k_emb(
    const float* __restrict__ emb, const float* __restrict__ W_exp,
    const float* __restrict__ b_exp, float* __restrict__ remb) {
  int u = threadIdx.x;
  int e = u & 63;
  int r = blockIdx.x * 4 + (u >> 6);
  const float* er = emb + (size_t)e * EMBD;
  const float* wr = W_exp + (size_t)r * EMBD;
  double a = (double)b_exp[r];
#pragma unroll 8
  for (int d4 = 0; d4 < EMBD / 4; ++d4) {
    float4 ev = *(const float4*)(er + d4 * 4);
    float4 wv = *(const float4*)(wr + d4 * 4);
    a += (double)ev.x * (double)wv.x;
    a += (double)ev.y * (double)wv.y;
    a += (double)ev.z * (double)wv.z;
    a += (double)ev.w * (double)wv.w;
  }
  remb[(size_t)r * NE + e] = (float)a;
}

// ---------------------------------------------------------------------------
// K2: C[d][e] = sum_r W_hid[r][d]*remb[r][e]  (fp64 acc), stored as fp16
// (hi,lo) of C*4096. Blocks 0..127: 16 d x 64 e tile, LDS-staged (W_hid read
// coalesced, exactly once). Block 128: c0.
// ---------------------------------------------------------------------------
__global__ __launch_bounds__(256) void k_proj(
    const float* __restrict__ W_hid, const float* __restrict__ b_hid,
    const float* __restrict__ remb, half2v* __restrict__ Cpack,
    float* __restrict__ c0) {
  int u = threadIdx.x;
  if (blockIdx.x == 128) {
    __shared__ double red[4][64];
    int e = u & 63, rq = u >> 6;
    double acc = 0.0;
#pragma unroll 8
    for (int i = 0; i < 256; ++i) {
      int r = rq * 256 + i;
      acc += (double)b_hid[r] * (double)remb[(size_t)r * NE + e];
    }
    red[rq][e] = acc;
    __syncthreads();
    if (u < 64) c0[u] = (float)(red[0][u] + red[1][u] + red[2][u] + red[3][u]);
    return;
  }

  __shared__ float Wl[64][16];   // 4 KB
  __shared__ float Rl[64][64];   // 16 KB
  const int dl = u & 15;
  const int eg = u >> 4;         // 0..15
  const int d0 = blockIdx.x * 16;
  double acc0 = 0.0, acc1 = 0.0, acc2 = 0.0, acc3 = 0.0;

  for (int r0 = 0; r0 < RKHS; r0 += 64) {
    __syncthreads();
#pragma unroll
    for (int i = 0; i < 4; ++i) {
      int qq = i * 256 + u;
      Wl[qq >> 4][qq & 15] = W_hid[(size_t)(r0 + (qq >> 4)) * DD + d0 + (qq & 15)];
    }
#pragma unroll
    for (int i = 0; i < 16; ++i) {
      int qq = i * 256 + u;
      Rl[qq >> 6][qq & 63] = remb[(size_t)(r0 + (qq >> 6)) * NE + (qq & 63)];
    }
    __syncthreads();
#pragma unroll 8
    for (int rr = 0; rr < 64; ++rr) {
      double wv = (double)Wl[rr][dl];
      acc0 += wv * (double)Rl[rr][eg * 4 + 0];
      acc1 += wv * (double)Rl[rr][eg * 4 + 1];
      acc2 += wv * (double)Rl[rr][eg * 4 + 2];
      acc3 += wv * (double)Rl[rr][eg * 4 + 3];
    }
  }
#define EMIT(J, ACC)                                                      \
  {                                                                       \
    float c = (float)((ACC) * 4096.0);                                    \
    _Float16 hi = (_Float16)c;                                            \
    _Float16 lo = (_Float16)(c - (float)hi);                              \
    half2v p; p.x = hi; p.y = lo;                                         \
    Cpack[(size_t)(d0 + dl) * NE + eg * 4 + (J)] = p;                     \
  }
  EMIT(0, acc0) EMIT(1, acc1) EMIT(2, acc2) EMIT(3, acc3)
#undef EMIT
}

// ---------------------------------------------------------------------------
// K3: pre-swizzle Cpack into MFMA B-fragment order.
// Fragment for (kk, group g, half h): lane l holds 8 fp16 =
//   C16[k = kk*32 + (l>>4)*8 + j][n = g*16 + (l&15)], j=0..7, packed 16B.
// Bsw uint4 index = ((kk*4+g)*2+h)*64 + l == flat thread id.
// ---------------------------------------------------------------------------
__global__ __launch_bounds__(256) void k_swz(
    const half2v* __restrict__ Cpack, uint4* __restrict__ Bsw) {
  int flat = blockIdx.x * 256 + threadIdx.x;   // 0..32767
  int lane = flat & 63;
  int h = (flat >> 6) & 1;
  int g = (flat >> 7) & 3;
  int kk = flat >> 9;
  int n = g * 16 + (lane & 15);
  int kb = kk * 32 + ((lane >> 4) & 3) * 8;
  half8 v;
#pragma unroll
  for (int j = 0; j < 8; ++j) {
    half2v p = Cpack[(size_t)(kb + j) * NE + n];
    v[j] = h ? p.y : p.x;
  }
  Bsw[flat] = __builtin_bit_cast(uint4, v);
}

// ---------------------------------------------------------------------------
// K4: main router. 2048 blocks x 128 threads (2 waves; wave w owns K-half w).
// SCRATCH-FREE pipelined K-loop: all buffered values are distinct named
// scalars (no local arrays -> nothing the compiler can demote to scratch;
// rounds 2/3 spilled, VGPR_Count 32/36, ~10 private round-trips per kk).
// Loop manually unrolled x2: buffers X/Y alternate with zero dynamic
// indexing. Per half-step: issue loads for the NEXT kk, then consume the
// current buffer -> partial vmcnt waits keep the next loads in flight.
// ---------------------------------------------------------------------------
#define LOADB(H0, L0, H1, L1, H2, L2, H3, L3, BQ)                          \
  H0 = (BQ)[0];   L0 = (BQ)[64];                                           \
  H1 = (BQ)[128]; L1 = (BQ)[192];                                          \
  H2 = (BQ)[256]; L2 = (BQ)[320];                                          \
  H3 = (BQ)[384]; L3 = (BQ)[448];

#define CVT1(I, X)                                                         \
  { float xx = (X); _Float16 hh = (_Float16)xx;                            \
    ah[I] = hh; al[I] = (_Float16)(xx - (float)hh); }

#define CONSUME(A0, A1, H0, L0, H1, L1, H2, L2, H3, L3)                    \
  {                                                                        \
    half8 ah, al;                                                          \
    CVT1(0, A0.x) CVT1(1, A0.y) CVT1(2, A0.z) CVT1(3, A0.w)                \
    CVT1(4, A1.x) CVT1(5, A1.y) CVT1(6, A1.z) CVT1(7, A1.w)                \
    const half8 bh0 = __builtin_bit_cast(half8, H0);                       \
    const half8 bL0 = __builtin_bit_cast(half8, L0);                       \
    const half8 bh1 = __builtin_bit_cast(half8, H1);                       \
    const half8 bL1 = __builtin_bit_cast(half8, L1);                       \
    const half8 bh2 = __builtin_bit_cast(half8, H2);                       \
    const half8 bL2 = __builtin_bit_cast(half8, L2);                       \
    const half8 bh3 = __builtin_bit_cast(half8, H3);                       \
    const half8 bL3 = __builtin_bit_cast(half8, L3);                       \
    acc0 = __builtin_amdgcn_mfma_f32_16x16x32_f16(ah, bh0, acc0, 0, 0, 0); \
    acc1 = __builtin_amdgcn_mfma_f32_16x16x32_f16(ah, bh1, acc1, 0, 0, 0); \
    acc2 = __builtin_amdgcn_mfma_f32_16x16x32_f16(ah, bh2, acc2, 0, 0, 0); \
    acc3 = __builtin_amdgcn_mfma_f32_16x16x32_f16(ah, bh3, acc3, 0, 0, 0); \
    acc0 = __builtin_amdgcn_mfma_f32_16x16x32_f16(al, bh0, acc0, 0, 0, 0); \
    acc1 = __builtin_amdgcn_mfma_f32_16x16x32_f16(al, bh1, acc1, 0, 0, 0); \
    acc2 = __builtin_amdgcn_mfma_f32_16x16x32_f16(al, bh2, acc2, 0, 0, 0); \
    acc3 = __builtin_amdgcn_mfma_f32_16x16x32_f16(al, bh3, acc3, 0, 0, 0); \
    acc0 = __builtin_amdgcn_mfma_f32_16x16x32_f16(ah, bL0, acc0, 0, 0, 0); \
    acc1 = __builtin_amdgcn_mfma_f32_16x16x32_f16(ah, bL1, acc1, 0, 0, 0); \
    acc2 = __builtin_amdgcn_mfma_f32_16x16x32_f16(ah, bL2, acc2, 0, 0, 0); \
    acc3 = __builtin_amdgcn_mfma_f32_16x16x32_f16(ah, bL3, acc3, 0, 0, 0); \
  }

__global__ __launch_bounds__(128, 3) void kernel_router(
    const float* __restrict__ in, const uint4* __restrict__ Bsw,
    const float* __restrict__ c0, float* __restrict__ out) {
  __shared__ float Lg[2][16][65];
  const int tid = threadIdx.x;
  const int l = tid & 63;
  const int w = tid >> 6;                     // K-half
  const size_t tok0 = (size_t)blockIdx.x * 16;
  const int q = (l >> 4) & 3;                 // quad
  const int col = l & 15;
  const float* arow = in + (tok0 + col) * DD + (size_t)w * (DD / 2) + q * 8;
  const uint4* bbase = Bsw + (size_t)w * 32 * 512 + l;

  f32x4 acc0 = {0.f, 0.f, 0.f, 0.f};
  f32x4 acc1 = {0.f, 0.f, 0.f, 0.f};
  f32x4 acc2 = {0.f, 0.f, 0.f, 0.f};
  f32x4 acc3 = {0.f, 0.f, 0.f, 0.f};

  uint4 xh0, xl0, xh1, xl1, xh2, xl2, xh3, xl3;
  uint4 yh0, yl0, yh1, yl1, yh2, yl2, yh3, yl3;
  float4 xa0, xa1, ya0, ya1;

  // preload X @ kk=0
  LOADB(xh0, xl0, xh1, xl1, xh2, xl2, xh3, xl3, bbase)
  xa0 = *(const float4*)(arow);
  xa1 = *(const float4*)(arow + 4);

  for (int kk = 0; kk < 32; kk += 2) {
    // load Y @ kk+1 (kk is even and <32, so kk+1 <= 31 always)
    {
      const uint4* bq = bbase + (size_t)(kk + 1) * 512;
      LOADB(yh0, yl0, yh1, yl1, yh2, yl2, yh3, yl3, bq)
      const float* ap = arow + (kk + 1) * 32;
      ya0 = *(const float4*)(ap);
      ya1 = *(const float4*)(ap + 4);
    }
    CONSUME(xa0, xa1, xh0, xl0, xh1, xl1, xh2, xl2, xh3, xl3)
    // load X @ min(kk+2, 31)  (last iter redundantly re-reads 31; harmless)
    {
      const int kn = (kk + 2 < 32) ? (kk + 2) : 31;
      const uint4* bq = bbase + (size_t)kn * 512;
      LOADB(xh0, xl0, xh1, xl1, xh2, xl2, xh3, xl3, bq)
      const float* ap = arow + kn * 32;
      xa0 = *(const float4*)(ap);
      xa1 = *(const float4*)(ap + 4);
    }
    CONSUME(ya0, ya1, yh0, yl0, yh1, yl1, yh2, yl2, yh3, yl3)
  }

  // epilogue: descale; wave 0 adds bias. C/D layout: col=lane&15, row=q*4+r.
  {
    const float inv = 1.0f / 4096.0f;
    const float base0 = w ? 0.f : c0[col];
    const float base1 = w ? 0.f : c0[16 + col];
    const float base2 = w ? 0.f : c0[32 + col];
    const float base3 = w ? 0.f : c0[48 + col];
#pragma unroll
    for (int r = 0; r < 4; ++r) {
      Lg[w][q * 4 + r][col]      = acc0[r] * inv + base0;
      Lg[w][q * 4 + r][16 + col] = acc1[r] * inv + base1;
      Lg[w][q * 4 + r][32 + col] = acc2[r] * inv + base2;
      Lg[w][q * 4 + r][48 + col] = acc3[r] * inv + base3;
    }
  }
  __syncthreads();

  if (tid < 16) {
    float m1 = Lg[0][tid][0] + Lg[1][tid][0];
    int i1 = 0;
#pragma unroll 8
    for (int e = 1; e < NE; ++e) {
      float v = Lg[0][tid][e] + Lg[1][tid][e];
      if (v > m1) { m1 = v; i1 = e; }
    }
    int i2 = (i1 == 0) ? 1 : 0;
    float m2 = Lg[0][tid][i2] + Lg[1][tid][i2];
#pragma unroll 8
    for (int e = 0; e < NE; ++e) {
      if (e == i1) continue;
      float v = Lg[0][tid][e] + Lg[1][tid][e];
      if (v > m2) { m2 = v; i2 = e; }
    }
    double ex = exp((double)m2 - (double)m1);
    double denom = 1.0 + ex;
    float rw1 = (float)(1.0 / denom);
    float rw2 = (float)(ex / denom);

    const size_t tg = tok0 + tid;
    *(float2*)(out + tg * 2) = make_float2((float)i1, (float)i2);
    *(float2*)(out + (size_t)NTOK * 2 + tg * 2) = make_float2(rw1, rw2);
  }
  // aux loss analytically constant: (K/E * 1/2) * E^2 = 64.0
  if (blockIdx.x == 0 && tid == 0) out[(size_t)NTOK * 4] = 64.0f;
}

// ---------------------------------------------------------------------------
extern "C" void kernel_launch(void* const* d_in, const int* in_sizes, int n_in,
                              void* d_out, int out_size, void* d_ws,
                              size_t ws_size, hipStream_t stream) {
  const float* input = (const float*)d_in[0];   // [4,8192,2048]
  const float* W_hid = (const float*)d_in[1];   // [1024,2048]
  const float* b_hid = (const float*)d_in[2];   // [1024]
  const float* W_exp = (const float*)d_in[3];   // [1024,128]
  const float* b_exp = (const float*)d_in[4];   // [1024]
  const float* emb = (const float*)d_in[5];     // [64,128]
  float* out = (float*)d_out;

  float* remb = (float*)((char*)d_ws + REMB_OFF);
  half2v* Cpack = (half2v*)((char*)d_ws + CPACK_OFF);
  uint4* Bsw = (uint4*)((char*)d_ws + BSW_OFF);
  float* c0 = (float*)((char*)d_ws + C0_OFF);

  k_emb<<<RKHS / 4, 256, 0, stream>>>(emb, W_exp, b_exp, remb);
  k_proj<<<129, 256, 0, stream>>>(W_hid, b_hid, remb, Cpack, c0);
  k_swz<<<128, 256, 0, stream>>>(Cpack, Bsw);
  kernel_router<<<NTOK / 16, 128, 0, stream>>>(input, Bsw, c0, out);
}